// Round 4
// baseline (402.251 us; speedup 1.0000x reference)
//
#include <hip/hip_runtime.h>

#define N_NODES 100000
#define N_EDGES 3200000
#define D_NODE 128
#define D_EDGE 16

#define RANGE_BITS 14
#define RANGE_SIZE 16384              // nodes per range -> 64 KB LDS accumulator
#define RANGE_MASK 16383
#define N_RANGES 7                    // 7*16384 >= 100000
#define NB 73                         // slices per range: 7*73=511 blocks, 2/CU

#define K1_THREADS 512
#define K1_EPT 8                      // edges per thread
#define K1_TILE (K1_THREADS * K1_EPT) // 4096

// ---- ws layout (float units) ----
#define WS_X      0                                   // 100000 floats
#define WS_GCNT   102400                              // 7 ints (bucket sizes)
#define WS_PAIRS  102432                              // int2[N_RANGES][N_EDGES]
#define WS_PART   (102432 + 2 * N_RANGES * N_EDGES)   // 7*NB*16384 floats
#define WS_TOTAL  (WS_PART + N_RANGES * NB * RANGE_SIZE)

// ---------------------------------------------------------------------------
// K0: compact node column (x[i]=nodes[i,0]) and zero the bucket counters.
// ---------------------------------------------------------------------------
__global__ void tmp_k0_extract(const float* __restrict__ nodes,
                               float* __restrict__ x,
                               int* __restrict__ gcnt) {
    int i = blockIdx.x * blockDim.x + threadIdx.x;
    if (i < N_NODES) x[i] = nodes[(size_t)i * D_NODE];
    if (i < N_RANGES) gcnt[i] = 0;
}

// ---------------------------------------------------------------------------
// K1: single pass over edges: msg = we*edges[e,0] + wn*x[send[e]], then
// partition (local_node, msg) pairs into 7 range buckets. Tile-level LDS
// counters + 7 global atomics per block reserve contiguous bucket space.
// ---------------------------------------------------------------------------
__global__ __launch_bounds__(K1_THREADS) void tmp_k1_partition(
        const float* __restrict__ x,
        const float* __restrict__ edges,
        const int*   __restrict__ senders,
        const int*   __restrict__ receivers,
        const float* __restrict__ w_node,
        const float* __restrict__ w_edge,
        int* __restrict__ gcnt,
        int2* __restrict__ pairs) {
    __shared__ int lcnt[N_RANGES];
    __shared__ int lbase[N_RANGES];
    if (threadIdx.x < N_RANGES) lcnt[threadIdx.x] = 0;
    __syncthreads();

    const float wn = w_node[0];
    const float we = w_edge[0];
    const int e0 = blockIdx.x * K1_TILE + (int)threadIdx.x * K1_EPT;
    const bool active = e0 < N_EDGES;   // N_EDGES%8==0 -> active threads do all 8

    int   b[K1_EPT], off[K1_EPT], loc[K1_EPT];
    float msg[K1_EPT];
    if (active) {
        int4 s0 = *(const int4*)(senders + e0);
        int4 s1 = *(const int4*)(senders + e0 + 4);
        int4 r0 = *(const int4*)(receivers + e0);
        int4 r1 = *(const int4*)(receivers + e0 + 4);
        int ss[K1_EPT] = {s0.x, s0.y, s0.z, s0.w, s1.x, s1.y, s1.z, s1.w};
        int rr[K1_EPT] = {r0.x, r0.y, r0.z, r0.w, r1.x, r1.y, r1.z, r1.w};
#pragma unroll
        for (int j = 0; j < K1_EPT; ++j) {
            // streaming read: edge column used once, keep LLC for pairs
            float ev = __builtin_nontemporal_load(edges + (size_t)(e0 + j) * D_EDGE);
            msg[j] = we * ev + wn * x[ss[j]];
            b[j]   = rr[j] >> RANGE_BITS;
            loc[j] = rr[j] & RANGE_MASK;
            off[j] = atomicAdd(&lcnt[b[j]], 1);   // LDS int atomic
        }
    }
    __syncthreads();
    if (threadIdx.x < N_RANGES)
        lbase[threadIdx.x] = atomicAdd(&gcnt[threadIdx.x], lcnt[threadIdx.x]);
    __syncthreads();
    if (active) {
#pragma unroll
        for (int j = 0; j < K1_EPT; ++j) {
            int2 p;
            p.x = loc[j];
            p.y = __float_as_int(msg[j]);
            pairs[(size_t)b[j] * N_EDGES + (size_t)(lbase[b[j]] + off[j])] = p;
        }
    }
}

// ---------------------------------------------------------------------------
// K2: per (range, slice) block: unconditional LDS accumulate of the bucket's
// pairs (each bucket read exactly once, LLC-hot), write full partial slice.
// ---------------------------------------------------------------------------
__global__ __launch_bounds__(1024) void tmp_k2_accum(
        const int2* __restrict__ pairs,
        const int*  __restrict__ gcnt,
        float* __restrict__ partials) {
    __shared__ float acc[RANGE_SIZE];   // 64 KB
    const int range = blockIdx.y;
    const int slice = blockIdx.x;

    for (int i = threadIdx.x; i < RANGE_SIZE; i += 1024) acc[i] = 0.f;
    __syncthreads();

    const int n = gcnt[range];
    int chunk = (n + NB - 1) / NB;
    int start = slice * chunk;
    int end = start + chunk; if (end > n) end = n;
    const int2* src = pairs + (size_t)range * N_EDGES;

    for (int i = start + (int)threadIdx.x; i < end; i += 1024) {
        int2 p = src[i];
        atomicAdd(&acc[p.x], __int_as_float(p.y));   // native ds_add_f32
    }
    __syncthreads();

    float* dst = partials + ((size_t)(range * NB + slice) << RANGE_BITS);
    for (int i = threadIdx.x; i < RANGE_SIZE; i += 1024) dst[i] = acc[i];
}

// ---------------------------------------------------------------------------
// K3: out[i] = wn*x[i] + b + sum over slices of partials[range(i)][s][local(i)]
// ---------------------------------------------------------------------------
__global__ void tmp_k3_reduce(const float* __restrict__ x,
                              const float* __restrict__ partials,
                              const float* __restrict__ w_node,
                              const float* __restrict__ b_node,
                              float* __restrict__ out) {
    int i = blockIdx.x * blockDim.x + threadIdx.x;
    if (i >= N_NODES) return;
    int range = i >> RANGE_BITS;
    int local = i & RANGE_MASK;
    float s = w_node[0] * x[i] + b_node[0];
    const float* p = partials + (((size_t)range * NB) << RANGE_BITS) + local;
#pragma unroll 4
    for (int bq = 0; bq < NB; ++bq) s += p[(size_t)bq << RANGE_BITS];
    out[i] = s;
}

// ---------------------------------------------------------------------------
// Fallback (workspace too small): round-1 direct atomic path.
// ---------------------------------------------------------------------------
__global__ void tmp_init_out(const float* __restrict__ nodes,
                             const float* __restrict__ w_node,
                             const float* __restrict__ b_node,
                             float* __restrict__ out) {
    int i = blockIdx.x * blockDim.x + threadIdx.x;
    if (i < N_NODES) out[i] = w_node[0] * nodes[(size_t)i * D_NODE] + b_node[0];
}

__global__ void tmp_edge_scatter_direct(const float* __restrict__ nodes,
                                        const float* __restrict__ edges,
                                        const int*   __restrict__ senders,
                                        const int*   __restrict__ receivers,
                                        const float* __restrict__ w_node,
                                        const float* __restrict__ w_edge,
                                        float* __restrict__ out) {
    const float wn = w_node[0];
    const float we = w_edge[0];
    int base = (blockIdx.x * blockDim.x + threadIdx.x) * 4;
    if (base + 3 < N_EDGES) {
        int4 s = *(const int4*)(senders + base);
        int4 r = *(const int4*)(receivers + base);
        atomicAdd(&out[r.x], we * edges[(size_t)(base + 0) * D_EDGE] + wn * nodes[(size_t)s.x * D_NODE]);
        atomicAdd(&out[r.y], we * edges[(size_t)(base + 1) * D_EDGE] + wn * nodes[(size_t)s.y * D_NODE]);
        atomicAdd(&out[r.z], we * edges[(size_t)(base + 2) * D_EDGE] + wn * nodes[(size_t)s.z * D_NODE]);
        atomicAdd(&out[r.w], we * edges[(size_t)(base + 3) * D_EDGE] + wn * nodes[(size_t)s.w * D_NODE]);
    } else {
        for (int e = base; e < N_EDGES; ++e) {
            atomicAdd(&out[receivers[e]],
                      we * edges[(size_t)e * D_EDGE] + wn * nodes[(size_t)senders[e] * D_NODE]);
        }
    }
}

extern "C" void kernel_launch(void* const* d_in, const int* in_sizes, int n_in,
                              void* d_out, int out_size, void* d_ws, size_t ws_size,
                              hipStream_t stream) {
    const float* nodes     = (const float*)d_in[0];
    const float* edges     = (const float*)d_in[1];
    const int*   senders   = (const int*)d_in[2];
    const int*   receivers = (const int*)d_in[3];
    const float* w_node    = (const float*)d_in[4];
    const float* w_edge    = (const float*)d_in[5];
    const float* b_node    = (const float*)d_in[6];
    float* out = (float*)d_out;
    float* ws  = (float*)d_ws;

    if (ws_size >= (size_t)WS_TOTAL * sizeof(float)) {
        float* x        = ws + WS_X;
        int*   gcnt     = (int*)(ws + WS_GCNT);
        int2*  pairs    = (int2*)(ws + WS_PAIRS);
        float* partials = ws + WS_PART;

        int threads = 256;
        tmp_k0_extract<<<(N_NODES + threads - 1) / threads, threads, 0, stream>>>(
            nodes, x, gcnt);

        int k1_blocks = (N_EDGES + K1_TILE - 1) / K1_TILE;
        tmp_k1_partition<<<k1_blocks, K1_THREADS, 0, stream>>>(
            x, edges, senders, receivers, w_node, w_edge, gcnt, pairs);

        dim3 grid2(NB, N_RANGES);
        tmp_k2_accum<<<grid2, 1024, 0, stream>>>(pairs, gcnt, partials);

        tmp_k3_reduce<<<(N_NODES + threads - 1) / threads, threads, 0, stream>>>(
            x, partials, w_node, b_node, out);
    } else {
        int threads = 256;
        tmp_init_out<<<(N_NODES + threads - 1) / threads, threads, 0, stream>>>(
            nodes, w_node, b_node, out);
        int n_thr = N_EDGES / 4;
        tmp_edge_scatter_direct<<<(n_thr + threads - 1) / threads, threads, 0, stream>>>(
            nodes, edges, senders, receivers, w_node, w_edge, out);
    }
}

// Round 5
// 366.215 us; speedup vs baseline: 1.0984x; 1.0984x over previous
//
#include <hip/hip_runtime.h>

#define N_NODES 100000
#define N_EDGES 3200000
#define D_NODE 128
#define D_EDGE 16

// Preferred config: 4 ranges x 32768 nodes (128 KB dynamic LDS), NB=64 slices
// -> K2 grid = 256 blocks = exactly 1 block/CU.
// Fallback config (if >64KB LDS opt-in fails): 7 ranges x 16384 (64 KB).
#define NB 64                      // edge slices; 3.2M = 64 * 50000 exactly

#define K1_THREADS 512
#define K1_EPT 8
#define K1_TILE (K1_THREADS * K1_EPT)

// ---- ws layout (float units) ----
#define WS_X      0                          // 100000 floats
#define WS_MSG    102400                     // 3.2M floats
#define WS_PART   (102400 + N_EDGES)         // partials: up to 4*NB*32768 floats
#define WS_TOTAL  (WS_PART + 4 * NB * 32768) // (7*NB*16384 is smaller)

// ---------------------------------------------------------------------------
// K0: compact node column so gathers are L2-resident (400 KB span).
// ---------------------------------------------------------------------------
__global__ void tmp_k0_extract(const float* __restrict__ nodes,
                               float* __restrict__ x) {
    int i = blockIdx.x * blockDim.x + threadIdx.x;
    if (i < N_NODES) x[i] = nodes[(size_t)i * D_NODE];
}

// ---------------------------------------------------------------------------
// K1: msg[e] = w_edge*edges[e,0] + w_node*x[senders[e]]  (coalesced store).
// Edge column is use-once: nontemporal, keep LLC for msg/recv re-reads.
// ---------------------------------------------------------------------------
__global__ __launch_bounds__(K1_THREADS) void tmp_k1_messages(
        const float* __restrict__ x,
        const float* __restrict__ edges,
        const int*   __restrict__ senders,
        const float* __restrict__ w_node,
        const float* __restrict__ w_edge,
        float* __restrict__ msg) {
    const float wn = w_node[0];
    const float we = w_edge[0];
    const int e0 = blockIdx.x * K1_TILE + (int)threadIdx.x * K1_EPT;
    if (e0 >= N_EDGES) return;          // N_EDGES%8==0 -> all 8 valid if e0 ok
    int4 s0 = *(const int4*)(senders + e0);
    int4 s1 = *(const int4*)(senders + e0 + 4);
    int ss[K1_EPT] = {s0.x, s0.y, s0.z, s0.w, s1.x, s1.y, s1.z, s1.w};
    float m[K1_EPT];
#pragma unroll
    for (int j = 0; j < K1_EPT; ++j) {
        float ev = __builtin_nontemporal_load(edges + (size_t)(e0 + j) * D_EDGE);
        m[j] = we * ev + wn * x[ss[j]];
    }
    *(float4*)(msg + e0)     = make_float4(m[0], m[1], m[2], m[3]);
    *(float4*)(msg + e0 + 4) = make_float4(m[4], m[5], m[6], m[7]);
}

// ---------------------------------------------------------------------------
// K2: filter-scan segment sum. blockIdx.y = node range (range_size nodes in
// dynamic LDS), blockIdx.x = edge slice of 50000 edges. recv+msg (25.6 MB)
// stay LLC-resident across the range passes. Full partial slice overwritten.
// ---------------------------------------------------------------------------
__global__ __launch_bounds__(1024) void tmp_k2_accum(
        const float* __restrict__ msg,
        const int*   __restrict__ receivers,
        float* __restrict__ partials,
        int range_bits) {
    extern __shared__ float acc[];
    const int range_size = 1 << range_bits;
    const int range_mask = range_size - 1;
    const int range = blockIdx.y;
    const int slice = blockIdx.x;

    for (int i = threadIdx.x; i < range_size; i += 1024) acc[i] = 0.f;
    __syncthreads();

    const int start = slice * (N_EDGES / NB);        // 50000, %4==0
    const int end   = start + (N_EDGES / NB);
    for (int e = start + (int)threadIdx.x * 4; e < end; e += 1024 * 4) {
        int4   r = *(const int4*)(receivers + e);
        float4 m = *(const float4*)(msg + e);
        if ((r.x >> range_bits) == range) atomicAdd(&acc[r.x & range_mask], m.x);
        if ((r.y >> range_bits) == range) atomicAdd(&acc[r.y & range_mask], m.y);
        if ((r.z >> range_bits) == range) atomicAdd(&acc[r.z & range_mask], m.z);
        if ((r.w >> range_bits) == range) atomicAdd(&acc[r.w & range_mask], m.w);
    }
    __syncthreads();

    float* dst = partials + ((size_t)(range * NB + slice) << range_bits);
    for (int i = threadIdx.x; i < range_size; i += 1024) dst[i] = acc[i];
}

// ---------------------------------------------------------------------------
// K3: out[i] = wn*x[i] + b + sum over slices of partials.
// ---------------------------------------------------------------------------
__global__ void tmp_k3_reduce(const float* __restrict__ x,
                              const float* __restrict__ partials,
                              const float* __restrict__ w_node,
                              const float* __restrict__ b_node,
                              float* __restrict__ out,
                              int range_bits) {
    int i = blockIdx.x * blockDim.x + threadIdx.x;
    if (i >= N_NODES) return;
    int range = i >> range_bits;
    int local = i & ((1 << range_bits) - 1);
    float s = w_node[0] * x[i] + b_node[0];
    const float* p = partials + (((size_t)range * NB) << range_bits) + local;
#pragma unroll 4
    for (int b = 0; b < NB; ++b) s += p[(size_t)b << range_bits];
    out[i] = s;
}

// ---------------------------------------------------------------------------
// Fallback (workspace too small): round-1 direct atomic path.
// ---------------------------------------------------------------------------
__global__ void tmp_init_out(const float* __restrict__ nodes,
                             const float* __restrict__ w_node,
                             const float* __restrict__ b_node,
                             float* __restrict__ out) {
    int i = blockIdx.x * blockDim.x + threadIdx.x;
    if (i < N_NODES) out[i] = w_node[0] * nodes[(size_t)i * D_NODE] + b_node[0];
}

__global__ void tmp_edge_scatter_direct(const float* __restrict__ nodes,
                                        const float* __restrict__ edges,
                                        const int*   __restrict__ senders,
                                        const int*   __restrict__ receivers,
                                        const float* __restrict__ w_node,
                                        const float* __restrict__ w_edge,
                                        float* __restrict__ out) {
    const float wn = w_node[0];
    const float we = w_edge[0];
    int base = (blockIdx.x * blockDim.x + threadIdx.x) * 4;
    if (base + 3 < N_EDGES) {
        int4 s = *(const int4*)(senders + base);
        int4 r = *(const int4*)(receivers + base);
        atomicAdd(&out[r.x], we * edges[(size_t)(base + 0) * D_EDGE] + wn * nodes[(size_t)s.x * D_NODE]);
        atomicAdd(&out[r.y], we * edges[(size_t)(base + 1) * D_EDGE] + wn * nodes[(size_t)s.y * D_NODE]);
        atomicAdd(&out[r.z], we * edges[(size_t)(base + 2) * D_EDGE] + wn * nodes[(size_t)s.z * D_NODE]);
        atomicAdd(&out[r.w], we * edges[(size_t)(base + 3) * D_EDGE] + wn * nodes[(size_t)s.w * D_NODE]);
    } else {
        for (int e = base; e < N_EDGES; ++e) {
            atomicAdd(&out[receivers[e]],
                      we * edges[(size_t)e * D_EDGE] + wn * nodes[(size_t)senders[e] * D_NODE]);
        }
    }
}

extern "C" void kernel_launch(void* const* d_in, const int* in_sizes, int n_in,
                              void* d_out, int out_size, void* d_ws, size_t ws_size,
                              hipStream_t stream) {
    const float* nodes     = (const float*)d_in[0];
    const float* edges     = (const float*)d_in[1];
    const int*   senders   = (const int*)d_in[2];
    const int*   receivers = (const int*)d_in[3];
    const float* w_node    = (const float*)d_in[4];
    const float* w_edge    = (const float*)d_in[5];
    const float* b_node    = (const float*)d_in[6];
    float* out = (float*)d_out;
    float* ws  = (float*)d_ws;

    if (ws_size >= (size_t)WS_TOTAL * sizeof(float)) {
        float* x        = ws + WS_X;
        float* msg      = ws + WS_MSG;
        float* partials = ws + WS_PART;

        // Try 128 KB dynamic LDS (4 ranges x 32768). Fall back to 64 KB
        // (7 ranges x 16384) if the opt-in attribute is unavailable.
        int range_bits = 15, n_ranges = 4;
        size_t lds_bytes = (size_t)(1 << range_bits) * sizeof(float);  // 128 KB
        hipError_t attr_ok = hipFuncSetAttribute(
            reinterpret_cast<const void*>(tmp_k2_accum),
            hipFuncAttributeMaxDynamicSharedMemorySize, (int)lds_bytes);
        if (attr_ok != hipSuccess) {
            range_bits = 14; n_ranges = 7;
            lds_bytes = (size_t)(1 << range_bits) * sizeof(float);     // 64 KB
        }

        int threads = 256;
        tmp_k0_extract<<<(N_NODES + threads - 1) / threads, threads, 0, stream>>>(
            nodes, x);

        int k1_blocks = (N_EDGES + K1_TILE - 1) / K1_TILE;
        tmp_k1_messages<<<k1_blocks, K1_THREADS, 0, stream>>>(
            x, edges, senders, w_node, w_edge, msg);

        dim3 grid2(NB, n_ranges);
        tmp_k2_accum<<<grid2, 1024, lds_bytes, stream>>>(
            msg, receivers, partials, range_bits);

        tmp_k3_reduce<<<(N_NODES + threads - 1) / threads, threads, 0, stream>>>(
            x, partials, w_node, b_node, out, range_bits);
    } else {
        int threads = 256;
        tmp_init_out<<<(N_NODES + threads - 1) / threads, threads, 0, stream>>>(
            nodes, w_node, b_node, out);
        int n_thr = N_EDGES / 4;
        tmp_edge_scatter_direct<<<(n_thr + threads - 1) / threads, threads, 0, stream>>>(
            nodes, edges, senders, receivers, w_node, w_edge, out);
    }
}

// Round 6
// 365.789 us; speedup vs baseline: 1.0997x; 1.0012x over previous
//
#include <hip/hip_runtime.h>

#define N_NODES 100000
#define N_EDGES 3200000
#define D_NODE 128
#define D_EDGE 16

#define NB 80                         // edge slices; 3.2M = 80 * 40000 exactly
#define SLICE_E (N_EDGES / NB)        // 40000

#define K1_THREADS 512
#define K1_EPT 8
#define K1_TILE (K1_THREADS * K1_EPT) // 4096

// ---- ws layout (float units) ----
#define WS_X      0                          // 100000 floats
#define WS_MSG    102400                     // 3.2M floats
#define WS_PART   (102400 + N_EDGES)         // partials: NB rows of N_NODES
#define WS_TOTAL  (WS_PART + NB * N_NODES)

// ---------------------------------------------------------------------------
// K0: compact node column so K1's gather is a 400 KB L2-resident array.
// ---------------------------------------------------------------------------
__global__ void tmp_k0_extract(const float* __restrict__ nodes,
                               float* __restrict__ x) {
    int i = blockIdx.x * blockDim.x + threadIdx.x;
    if (i < N_NODES) x[i] = nodes[(size_t)i * D_NODE];
}

// ---------------------------------------------------------------------------
// K1: msg[e] = w_edge*edges[e,0] + w_node*x[senders[e]].
// Lane-contiguous: a wave's 64 edge-line fetches are 64 consecutive 64 B
// cachelines (4 KB burst) -> best DRAM efficiency for the 205 MB column read.
// ---------------------------------------------------------------------------
__global__ __launch_bounds__(K1_THREADS) void tmp_k1_messages(
        const float* __restrict__ x,
        const float* __restrict__ edges,
        const int*   __restrict__ senders,
        const float* __restrict__ w_node,
        const float* __restrict__ w_edge,
        float* __restrict__ msg) {
    const float wn = w_node[0];
    const float we = w_edge[0];
    const int tile = blockIdx.x * K1_TILE;
#pragma unroll
    for (int j = 0; j < K1_EPT; ++j) {
        int e = tile + j * K1_THREADS + (int)threadIdx.x;
        if (e < N_EDGES) {
            float ev = __builtin_nontemporal_load(edges + (size_t)e * D_EDGE);
            int   s  = senders[e];
            msg[e] = we * ev + wn * x[s];
        }
    }
}

// ---------------------------------------------------------------------------
// K2: filter-scan segment sum. blockIdx.y = node range (range_floats nodes in
// dynamic LDS, up to 160 KB), blockIdx.x = edge slice (40000 edges).
// msg+recv (25.6 MB) stay LLC-resident across range passes. Partials are
// stored compact: row s = partials[s*N_NODES + node]; block (r,s) overwrites
// its [lo, lo+span) span -> no pre-zeroing, coalesced, NB*400KB total.
// ---------------------------------------------------------------------------
__global__ __launch_bounds__(1024) void tmp_k2_accum(
        const float* __restrict__ msg,
        const int*   __restrict__ receivers,
        float* __restrict__ partials,
        int range_floats) {
    extern __shared__ float acc[];
    const int lo   = blockIdx.y * range_floats;
    int span = N_NODES - lo; if (span > range_floats) span = range_floats;
    const unsigned uspan = (unsigned)span;
    const int slice = blockIdx.x;

    for (int i = threadIdx.x; i < span; i += 1024) acc[i] = 0.f;
    __syncthreads();

    const int start = slice * SLICE_E;
    const int end   = start + SLICE_E;
    for (int e = start + (int)threadIdx.x * 4; e < end; e += 1024 * 4) {
        int4   r = *(const int4*)(receivers + e);
        float4 m = *(const float4*)(msg + e);
        unsigned ux = (unsigned)(r.x - lo);
        unsigned uy = (unsigned)(r.y - lo);
        unsigned uz = (unsigned)(r.z - lo);
        unsigned uw = (unsigned)(r.w - lo);
        if (ux < uspan) atomicAdd(&acc[ux], m.x);
        if (uy < uspan) atomicAdd(&acc[uy], m.y);
        if (uz < uspan) atomicAdd(&acc[uz], m.z);
        if (uw < uspan) atomicAdd(&acc[uw], m.w);
    }
    __syncthreads();

    float* dst = partials + (size_t)slice * N_NODES + lo;
    for (int i = threadIdx.x * 4; i < span; i += 1024 * 4) {
        *(float4*)(dst + i) = *(const float4*)(acc + i);   // span % 4 == 0
    }
}

// ---------------------------------------------------------------------------
// K3: out[i] = wn*x[i] + b + sum_s partials[s*N_NODES + i]
// ---------------------------------------------------------------------------
__global__ void tmp_k3_reduce(const float* __restrict__ x,
                              const float* __restrict__ partials,
                              const float* __restrict__ w_node,
                              const float* __restrict__ b_node,
                              float* __restrict__ out) {
    int i = blockIdx.x * blockDim.x + threadIdx.x;
    if (i >= N_NODES) return;
    float s = w_node[0] * x[i] + b_node[0];
    const float* p = partials + i;
#pragma unroll 4
    for (int b = 0; b < NB; ++b) s += p[(size_t)b * N_NODES];
    out[i] = s;
}

// ---------------------------------------------------------------------------
// Fallback (workspace too small): round-1 direct atomic path.
// ---------------------------------------------------------------------------
__global__ void tmp_init_out(const float* __restrict__ nodes,
                             const float* __restrict__ w_node,
                             const float* __restrict__ b_node,
                             float* __restrict__ out) {
    int i = blockIdx.x * blockDim.x + threadIdx.x;
    if (i < N_NODES) out[i] = w_node[0] * nodes[(size_t)i * D_NODE] + b_node[0];
}

__global__ void tmp_edge_scatter_direct(const float* __restrict__ nodes,
                                        const float* __restrict__ edges,
                                        const int*   __restrict__ senders,
                                        const int*   __restrict__ receivers,
                                        const float* __restrict__ w_node,
                                        const float* __restrict__ w_edge,
                                        float* __restrict__ out) {
    const float wn = w_node[0];
    const float we = w_edge[0];
    int base = (blockIdx.x * blockDim.x + threadIdx.x) * 4;
    if (base + 3 < N_EDGES) {
        int4 s = *(const int4*)(senders + base);
        int4 r = *(const int4*)(receivers + base);
        atomicAdd(&out[r.x], we * edges[(size_t)(base + 0) * D_EDGE] + wn * nodes[(size_t)s.x * D_NODE]);
        atomicAdd(&out[r.y], we * edges[(size_t)(base + 1) * D_EDGE] + wn * nodes[(size_t)s.y * D_NODE]);
        atomicAdd(&out[r.z], we * edges[(size_t)(base + 2) * D_EDGE] + wn * nodes[(size_t)s.z * D_NODE]);
        atomicAdd(&out[r.w], we * edges[(size_t)(base + 3) * D_EDGE] + wn * nodes[(size_t)s.w * D_NODE]);
    } else {
        for (int e = base; e < N_EDGES; ++e) {
            atomicAdd(&out[receivers[e]],
                      we * edges[(size_t)e * D_EDGE] + wn * nodes[(size_t)senders[e] * D_NODE]);
        }
    }
}

extern "C" void kernel_launch(void* const* d_in, const int* in_sizes, int n_in,
                              void* d_out, int out_size, void* d_ws, size_t ws_size,
                              hipStream_t stream) {
    const float* nodes     = (const float*)d_in[0];
    const float* edges     = (const float*)d_in[1];
    const int*   senders   = (const int*)d_in[2];
    const int*   receivers = (const int*)d_in[3];
    const float* w_node    = (const float*)d_in[4];
    const float* w_edge    = (const float*)d_in[5];
    const float* b_node    = (const float*)d_in[6];
    float* out = (float*)d_out;
    float* ws  = (float*)d_ws;

    if (ws_size >= (size_t)WS_TOTAL * sizeof(float)) {
        float* x        = ws + WS_X;
        float* msg      = ws + WS_MSG;
        float* partials = ws + WS_PART;

        // LDS size fallback chain: 160 KB (3 passes) -> 128 KB (4) -> 64 KB (7)
        int range_floats = 40960;                       // 160 KB
        size_t lds_bytes = (size_t)range_floats * sizeof(float);
        if (hipFuncSetAttribute(reinterpret_cast<const void*>(tmp_k2_accum),
                                hipFuncAttributeMaxDynamicSharedMemorySize,
                                (int)lds_bytes) != hipSuccess) {
            range_floats = 32768;                       // 128 KB
            lds_bytes = (size_t)range_floats * sizeof(float);
            if (hipFuncSetAttribute(reinterpret_cast<const void*>(tmp_k2_accum),
                                    hipFuncAttributeMaxDynamicSharedMemorySize,
                                    (int)lds_bytes) != hipSuccess) {
                range_floats = 16384;                   // 64 KB
                lds_bytes = (size_t)range_floats * sizeof(float);
            }
        }
        int n_ranges = (N_NODES + range_floats - 1) / range_floats;

        int threads = 256;
        tmp_k0_extract<<<(N_NODES + threads - 1) / threads, threads, 0, stream>>>(
            nodes, x);

        int k1_blocks = (N_EDGES + K1_TILE - 1) / K1_TILE;
        tmp_k1_messages<<<k1_blocks, K1_THREADS, 0, stream>>>(
            x, edges, senders, w_node, w_edge, msg);

        dim3 grid2(NB, n_ranges);
        tmp_k2_accum<<<grid2, 1024, lds_bytes, stream>>>(
            msg, receivers, partials, range_floats);

        tmp_k3_reduce<<<(N_NODES + threads - 1) / threads, threads, 0, stream>>>(
            x, partials, w_node, b_node, out);
    } else {
        int threads = 256;
        tmp_init_out<<<(N_NODES + threads - 1) / threads, threads, 0, stream>>>(
            nodes, w_node, b_node, out);
        int n_thr = N_EDGES / 4;
        tmp_edge_scatter_direct<<<(n_thr + threads - 1) / threads, threads, 0, stream>>>(
            nodes, edges, senders, receivers, w_node, w_edge, out);
    }
}